// Round 3
// baseline (18.074 us; speedup 1.0000x reference)
//
#include <hip/hip_runtime.h>

#define NPART 512
#define BATCH 128
#define SPLITS 8          // blocks per batch; block s covers k in [1+32s, 32+32s]
#define NTH 256           // thread owns rows 2t, 2t+1

// Parity-split LDS layout: even particle p=2m -> slot m (m in [0,384)),
// odd particle p=2m+1 -> slot 384+m. Mirror: particle 512+q == q, and
// slot(p+512) = slot(p)+256. All inner-loop reads become stride-1 float4.

__device__ __forceinline__ void pair_term(const float4 a, const float4 b,
                                          float& acc12, float& acc6) {
    float dx = a.x - b.x, dy = a.y - b.y, dz = a.z - b.z;
    float r2 = fmaf(dx, dx, fmaf(dy, dy, dz * dz));
    float i2 = __builtin_amdgcn_rcpf(r2);
    float i6 = i2 * i2 * i2;
    acc12 = fmaf(i6, i6, acc12);
    acc6 += i6;
}

__global__ __launch_bounds__(NTH, 4) void lj_main(
    const float* __restrict__ x, float* __restrict__ out) {
    const int bid = blockIdx.x;
    const int b = bid >> 3;
    const int s = bid & 7;
    const int tid = threadIdx.x;

    __shared__ float4 sp[768];   // 384 even-slots + 384 odd-slots (incl. mirror)
    __shared__ float wred[4];
    __shared__ float wspr[4][4];

    // Stage: coalesced global reads, parity-slot scattered LDS writes.
    const float* xb = x + (size_t)b * (NPART * 3);
    float* spf = reinterpret_cast<float*>(sp);
    #pragma unroll
    for (int t = 0; t < 6; ++t) {
        const int idx = tid + t * NTH;      // 0..1535
        const float v = xb[idx];
        const int p = idx / 3;
        const int c = idx - p * 3;
        const int sl = (p >> 1) + ((p & 1) ? 384 : 0);
        spf[sl * 4 + c] = v;
        if (p < 256) spf[(sl + 256) * 4 + c] = v;   // mirror particles 512..767
    }
    __syncthreads();

    const float4 pi0 = sp[tid];          // particle 2t
    const float4 pi1 = sp[384 + tid];    // particle 2t+1

    // base = sp + t + a, a = (k0>>1) = 16s  (k0 = 1+32s, odd)
    const float4* base = sp + tid + 16 * s;

    float acc6 = 0.0f, acc12 = 0.0f;

    // kk=0 (K=k0 odd): row0 only, offset 384
    pair_term(pi0, base[384], acc12, acc6);
    #pragma unroll
    for (int m = 1; m <= 15; ++m) {
        const float4 Pe = base[m];        // kk=2m-1, K even
        pair_term(pi0, Pe, acc12, acc6);
        pair_term(pi1, Pe, acc12, acc6);
        const float4 Po = base[384 + m];  // kk=2m, K odd
        pair_term(pi0, Po, acc12, acc6);
        pair_term(pi1, Po, acc12, acc6);
    }
    {
        const float4 Pe = base[16];       // kk=31, K even
        pair_term(pi0, Pe, acc12, acc6);
        pair_term(pi1, Pe, acc12, acc6);
    }
    pair_term(pi1, base[400], acc12, acc6);   // kk=32 (K odd): row1 only

    // k=256 pairs were counted at full weight by split s=7 for both rows,
    // but each {i, i+256} pair appears from both endpoints -> weight 1/2.
    if (s == SPLITS - 1) {
        {
            const float4 P = sp[tid + 128];       // J = 2t+256 (even)
            float dx = pi0.x - P.x, dy = pi0.y - P.y, dz = pi0.z - P.z;
            float r2 = fmaf(dx, dx, fmaf(dy, dy, dz * dz));
            float i2 = __builtin_amdgcn_rcpf(r2);
            float i6 = i2 * i2 * i2;
            acc12 -= 0.5f * i6 * i6;
            acc6 -= 0.5f * i6;
        }
        {
            const float4 P = sp[tid + 512];       // J = 2t+257 (odd)
            float dx = pi1.x - P.x, dy = pi1.y - P.y, dz = pi1.z - P.z;
            float r2 = fmaf(dx, dx, fmaf(dy, dy, dz * dz));
            float i2 = __builtin_amdgcn_rcpf(r2);
            float i6 = i2 * i2 * i2;
            acc12 -= 0.5f * i6 * i6;
            acc6 -= 0.5f * i6;
        }
    }

    float pot = 4.0f * (acc12 - acc6);

    #pragma unroll
    for (int off = 32; off; off >>= 1) pot += __shfl_down(pot, off, 64);

    // Harmonic COM restraint: s==0 blocks only (thread owns particles 2t,2t+1)
    float sx = 0.0f, sy = 0.0f, sz = 0.0f, ssq = 0.0f;
    if (s == 0) {
        sx = pi0.x + pi1.x;
        sy = pi0.y + pi1.y;
        sz = pi0.z + pi1.z;
        ssq = pi0.x * pi0.x + pi0.y * pi0.y + pi0.z * pi0.z
            + pi1.x * pi1.x + pi1.y * pi1.y + pi1.z * pi1.z;
        #pragma unroll
        for (int off = 32; off; off >>= 1) {
            sx  += __shfl_down(sx,  off, 64);
            sy  += __shfl_down(sy,  off, 64);
            sz  += __shfl_down(sz,  off, 64);
            ssq += __shfl_down(ssq, off, 64);
        }
    }

    const int wave = tid >> 6;
    const int lane = tid & 63;
    if (lane == 0) {
        wred[wave] = pot;
        wspr[wave][0] = sx; wspr[wave][1] = sy;
        wspr[wave][2] = sz; wspr[wave][3] = ssq;
    }
    __syncthreads();

    if (tid == 0) {
        float P = 0.0f, SX = 0.0f, SY = 0.0f, SZ = 0.0f, SS = 0.0f;
        #pragma unroll
        for (int w = 0; w < 4; ++w) {
            P += wred[w];
            SX += wspr[w][0]; SY += wspr[w][1];
            SZ += wspr[w][2]; SS += wspr[w][3];
        }
        float res = P;
        if (s == 0) {
            // 0.5*K*sum(rel^2), K=0.5 -> 0.25*(ssq - |sum|^2/N)
            res += 0.25f * (SS - (SX * SX + SY * SY + SZ * SZ) * (1.0f / NPART));
        }
        atomicAdd(&out[b], -res);
    }
}

extern "C" void kernel_launch(void* const* d_in, const int* in_sizes, int n_in,
                              void* d_out, int out_size, void* d_ws, size_t ws_size,
                              hipStream_t stream) {
    const float* x = (const float*)d_in[0];
    float* out = (float*)d_out;

    hipMemsetAsync(out, 0, BATCH * sizeof(float), stream);
    lj_main<<<BATCH * SPLITS, NTH, 0, stream>>>(x, out);
}

// Round 4
// 17.724 us; speedup vs baseline: 1.0197x; 1.0197x over previous
//
#include <hip/hip_runtime.h>

#define NPART 512
#define BATCH 128
#define NTH 1024

// Parity-split LDS layout: even particle p=2m -> slot m (region A, m<384),
// odd particle p=2m+1 -> slot 384+m (region B). Mirror: particle 512+q == q
// at slot(q)+256. All inner-loop reads are stride-1 float4 across lanes
// (conflict-free ds_read_b128).

__device__ __forceinline__ void pair_term(const float4 a, const float4 b,
                                          float& acc12, float& acc6) {
    float dx = a.x - b.x, dy = a.y - b.y, dz = a.z - b.z;
    float r2 = fmaf(dx, dx, fmaf(dy, dy, dz * dz));
    float i2 = __builtin_amdgcn_rcpf(r2);
    float i6 = i2 * i2 * i2;
    acc12 = fmaf(i6, i6, acc12);
    acc6 += i6;
}

// One block per batch: 1024 threads = (t in [0,256)) x (h in [0,4)).
// Thread (t,h) owns rows 2t, 2t+1 with K in [64h+1, 64h+64].
__global__ __launch_bounds__(NTH, 4) void lj_full(
    const float* __restrict__ x, float* __restrict__ out) {
    const int b = blockIdx.x;
    const int tid = threadIdx.x;

    __shared__ float4 sp[768];
    __shared__ float wred[16];
    __shared__ float wspr[16][4];

    // Stage 1536 floats; scatter to parity slots (+ mirror for p<256).
    const float* xb = x + (size_t)b * (NPART * 3);
    float* spf = reinterpret_cast<float*>(sp);
    {
        const int idx = tid;                 // 0..1023
        const float v = xb[idx];
        const int p = idx / 3;
        const int c = idx - p * 3;
        const int sl = (p >> 1) + ((p & 1) ? 384 : 0);
        spf[sl * 4 + c] = v;
        if (p < 256) spf[(sl + 256) * 4 + c] = v;
    }
    if (tid < 512) {
        const int idx = tid + 1024;          // 1024..1535
        const float v = xb[idx];
        const int p = idx / 3;
        const int c = idx - p * 3;
        const int sl = (p >> 1) + ((p & 1) ? 384 : 0);
        spf[sl * 4 + c] = v;
        // p >= 341 here, no mirror needed
    }
    __syncthreads();

    const int t = tid & 255;
    const int h = tid >> 8;
    const float4 pi0 = sp[t];          // particle 2t
    const float4 pi1 = sp[384 + t];    // particle 2t+1
    const float4* base = sp + t + 32 * h;

    float a12_0 = 0.0f, a6_0 = 0.0f, a12_1 = 0.0f, a6_1 = 0.0f;

    // Region B m=0: row0, K=64h+1
    pair_term(pi0, base[384], a12_0, a6_0);
    #pragma unroll 4
    for (int m = 1; m < 32; ++m) {
        const float4 Pe = base[m];         // particle 2(t+32h+m)
        pair_term(pi0, Pe, a12_0, a6_0);   // row0: K=64h+2m (even)
        pair_term(pi1, Pe, a12_1, a6_1);   // row1: K=64h+2m-1 (odd)
        const float4 Po = base[384 + m];   // particle 2(t+32h+m)+1
        pair_term(pi0, Po, a12_0, a6_0);   // row0: K=64h+2m+1 (odd)
        pair_term(pi1, Po, a12_1, a6_1);   // row1: K=64h+2m (even)
    }
    {
        const float4 Pe = base[32];
        pair_term(pi0, Pe, a12_0, a6_0);   // row0: K=64h+64
        pair_term(pi1, Pe, a12_1, a6_1);   // row1: K=64h+63
    }
    pair_term(pi1, base[384 + 32], a12_1, a6_1);   // row1: K=64h+64

    // K=256 pairs (h==3, m=32 terms) appear from both endpoints globally:
    // subtract half weight once per row.
    if (h == 3) {
        {
            const float4 P = sp[t + 128];       // particle 2t+256
            float dx = pi0.x - P.x, dy = pi0.y - P.y, dz = pi0.z - P.z;
            float r2 = fmaf(dx, dx, fmaf(dy, dy, dz * dz));
            float i2 = __builtin_amdgcn_rcpf(r2);
            float i6 = i2 * i2 * i2;
            a12_0 -= 0.5f * i6 * i6;
            a6_0 -= 0.5f * i6;
        }
        {
            const float4 P = sp[t + 512];       // particle 2t+257
            float dx = pi1.x - P.x, dy = pi1.y - P.y, dz = pi1.z - P.z;
            float r2 = fmaf(dx, dx, fmaf(dy, dy, dz * dz));
            float i2 = __builtin_amdgcn_rcpf(r2);
            float i6 = i2 * i2 * i2;
            a12_1 -= 0.5f * i6 * i6;
            a6_1 -= 0.5f * i6;
        }
    }

    float pot = 4.0f * ((a12_0 + a12_1) - (a6_0 + a6_1));

    #pragma unroll
    for (int off = 32; off; off >>= 1) pot += __shfl_down(pot, off, 64);

    // Harmonic COM restraint: h==0 threads own particles 2t, 2t+1 exactly once.
    float sx = 0.0f, sy = 0.0f, sz = 0.0f, ssq = 0.0f;
    if (h == 0) {
        sx = pi0.x + pi1.x;
        sy = pi0.y + pi1.y;
        sz = pi0.z + pi1.z;
        ssq = pi0.x * pi0.x + pi0.y * pi0.y + pi0.z * pi0.z
            + pi1.x * pi1.x + pi1.y * pi1.y + pi1.z * pi1.z;
        #pragma unroll
        for (int off = 32; off; off >>= 1) {
            sx  += __shfl_down(sx,  off, 64);
            sy  += __shfl_down(sy,  off, 64);
            sz  += __shfl_down(sz,  off, 64);
            ssq += __shfl_down(ssq, off, 64);
        }
    }

    const int wave = tid >> 6;
    const int lane = tid & 63;
    if (lane == 0) {
        wred[wave] = pot;
        wspr[wave][0] = sx; wspr[wave][1] = sy;
        wspr[wave][2] = sz; wspr[wave][3] = ssq;
    }
    __syncthreads();

    if (tid == 0) {
        float P = 0.0f, SX = 0.0f, SY = 0.0f, SZ = 0.0f, SS = 0.0f;
        #pragma unroll
        for (int w = 0; w < 16; ++w) {
            P += wred[w];
            SX += wspr[w][0]; SY += wspr[w][1];
            SZ += wspr[w][2]; SS += wspr[w][3];
        }
        // 0.5*K_spring*sum(rel^2), K_spring=0.5 -> 0.25*(ssq - |sum|^2/N)
        const float res = P + 0.25f * (SS - (SX * SX + SY * SY + SZ * SZ) * (1.0f / NPART));
        out[b] = -res;
    }
}

extern "C" void kernel_launch(void* const* d_in, const int* in_sizes, int n_in,
                              void* d_out, int out_size, void* d_ws, size_t ws_size,
                              hipStream_t stream) {
    const float* x = (const float*)d_in[0];
    float* out = (float*)d_out;
    lj_full<<<BATCH, NTH, 0, stream>>>(x, out);
}

// Round 5
// 13.009 us; speedup vs baseline: 1.3894x; 1.3625x over previous
//
#include <hip/hip_runtime.h>

#define NPART 512
#define BATCH 128

// Quad-split LDS layout: particle p -> region (p&3), slot (p>>2).
// Regions are 192 float4 each (particles mirrored to p<768: slot(p+512)=slot(p)+128).
// Window reads are stride-1 float4 across lanes (conflict-free ds_read_b128),
// with compile-time immediate offsets under full unroll.
//
// grid = 256 blocks = (batch b, half s). block = 1024 threads = (t in [0,128)) x (h in [0,8)).
// Thread (t,h,s): rows i = 4t+r (r=0..3), K in [16X+1, 16X+16], X = 8s+h in [0,16).
// Each unordered pair with circular distance d<256 counted once; d=256 counted
// twice at full weight, corrected by -0.5 in the X==15 threads.

__global__ __launch_bounds__(1024, 4) void lj_main(
    const float* __restrict__ x, float* __restrict__ ws) {
    const int bid = blockIdx.x;
    const int b = bid >> 1;
    const int s = bid & 1;
    const int tid = threadIdx.x;
    const int t = tid & 127;
    const int h = tid >> 7;

    __shared__ float4 sp[768];       // 4 regions x 192 float4 = 12 KB
    __shared__ float wred[16];
    __shared__ float wspr[2][4];

    // ---- stage 1536 floats (+768 mirror floats) into quad-split layout ----
    const float* xb = x + (size_t)b * (NPART * 3);
    float* spf = reinterpret_cast<float*>(sp);
    {
        const int idx = tid;                 // 0..1023
        const float v = xb[idx];
        const int p = idx / 3;
        const int c = idx - 3 * p;
        const int sl = (p & 3) * 192 + (p >> 2);
        spf[4 * sl + c] = v;
        if (p < 256) spf[4 * (sl + 128) + c] = v;   // mirror p+512
    }
    if (tid < 512) {
        const int idx = tid + 1024;          // 1024..1535 (p >= 341, no mirror)
        const float v = xb[idx];
        const int p = idx / 3;
        const int c = idx - 3 * p;
        const int sl = (p & 3) * 192 + (p >> 2);
        spf[4 * sl + c] = v;
    }
    __syncthreads();

    // region pointers at slot t
    const float4* R0 = sp + t;
    const float4* R1 = sp + 192 + t;
    const float4* R2 = sp + 384 + t;
    const float4* R3 = sp + 576 + t;

    const float4 pi0 = R0[0];   // particle 4t
    const float4 pi1 = R1[0];   // particle 4t+1
    const float4 pi2 = R2[0];   // particle 4t+2
    const float4 pi3 = R3[0];   // particle 4t+3

    const int X = 8 * s + h;     // 0..15 ; k0 = 16X+1 ; J = 4t + k0
    const int B4 = 4 * X;        // window slot offset (J>>2 = t + 4X)

    float accA = 0.0f, accB = 0.0f;

    // acc += i6*(i6-1) ; pot = 4*acc
    #define PT(PI, W, ACC) do {                                   \
        const float dx_ = (PI).x - (W).x;                         \
        const float dy_ = (PI).y - (W).y;                         \
        const float dz_ = (PI).z - (W).z;                         \
        const float r2_ = fmaf(dx_, dx_, fmaf(dy_, dy_, dz_ * dz_)); \
        const float i2_ = __builtin_amdgcn_rcpf(r2_);             \
        const float i6_ = i2_ * i2_ * i2_;                        \
        ACC = fmaf(i6_, i6_ - 1.0f, ACC);                         \
    } while (0)

    // sliding window w[m] holds particle j = J + m  (J = 4t + 16X + 1)
    float4 w[19];
    w[0] = R1[B4];               // j = J   : region 1, slot t+4X
    w[1] = R2[B4];               // j = J+1 : region 2
    w[2] = R3[B4];               // j = J+2 : region 3
    #pragma unroll
    for (int m = 0; m < 16; ++m) {
        const int q = B4 + 1 + (m >> 2);   // slot offset of j = J+3+m
        const int rg = m & 3;              // region of j = J+3+m
        w[m + 3] = (rg == 0) ? R0[q] : (rg == 1) ? R1[q] : (rg == 2) ? R2[q] : R3[q];
        PT(pi0, w[m], accA);      // K = k0 + m
        PT(pi1, w[m + 1], accA);
        PT(pi2, w[m + 2], accB);
        PT(pi3, w[m + 3], accB);
    }

    // K=256 pairs (X==15, m==15) were counted at full weight from both
    // endpoints globally -> subtract half once per row. j = 4t+r+256.
    if (X == 15) {
        #define CORR(PI, W, ACC) do {                             \
            const float dx_ = (PI).x - (W).x;                     \
            const float dy_ = (PI).y - (W).y;                     \
            const float dz_ = (PI).z - (W).z;                     \
            const float r2_ = fmaf(dx_, dx_, fmaf(dy_, dy_, dz_ * dz_)); \
            const float i2_ = __builtin_amdgcn_rcpf(r2_);         \
            const float i6_ = i2_ * i2_ * i2_;                    \
            ACC -= 0.5f * i6_ * (i6_ - 1.0f);                     \
        } while (0)
        CORR(pi0, R0[64], accA);
        CORR(pi1, R1[64], accA);
        CORR(pi2, R2[64], accB);
        CORR(pi3, R3[64], accB);
        #undef CORR
    }
    #undef PT

    float pot = 4.0f * (accA + accB);

    #pragma unroll
    for (int off = 32; off; off >>= 1) pot += __shfl_down(pot, off, 64);

    // Harmonic COM restraint: X==0 threads (s==0, h==0) own particles
    // 4t..4t+3 exactly once -> waves 0,1 of the s==0 block.
    float sx = 0.0f, sy = 0.0f, sz = 0.0f, ssq = 0.0f;
    if (X == 0) {
        sx = pi0.x + pi1.x + pi2.x + pi3.x;
        sy = pi0.y + pi1.y + pi2.y + pi3.y;
        sz = pi0.z + pi1.z + pi2.z + pi3.z;
        ssq = pi0.x * pi0.x + pi0.y * pi0.y + pi0.z * pi0.z
            + pi1.x * pi1.x + pi1.y * pi1.y + pi1.z * pi1.z
            + pi2.x * pi2.x + pi2.y * pi2.y + pi2.z * pi2.z
            + pi3.x * pi3.x + pi3.y * pi3.y + pi3.z * pi3.z;
        #pragma unroll
        for (int off = 32; off; off >>= 1) {
            sx  += __shfl_down(sx,  off, 64);
            sy  += __shfl_down(sy,  off, 64);
            sz  += __shfl_down(sz,  off, 64);
            ssq += __shfl_down(ssq, off, 64);
        }
    }

    const int wave = tid >> 6;
    const int lane = tid & 63;
    if (lane == 0) {
        wred[wave] = pot;
        if (wave < 2 && s == 0) {
            wspr[wave][0] = sx; wspr[wave][1] = sy;
            wspr[wave][2] = sz; wspr[wave][3] = ssq;
        }
    }
    __syncthreads();

    if (tid == 0) {
        float P = 0.0f;
        #pragma unroll
        for (int w2 = 0; w2 < 16; ++w2) P += wred[w2];
        float res = P;
        if (s == 0) {
            const float SX = wspr[0][0] + wspr[1][0];
            const float SY = wspr[0][1] + wspr[1][1];
            const float SZ = wspr[0][2] + wspr[1][2];
            const float SS = wspr[0][3] + wspr[1][3];
            // 0.5*K_spring*sum(rel^2), K_spring=0.5 -> 0.25*(ssq - |S|^2/N)
            res += 0.25f * (SS - (SX * SX + SY * SY + SZ * SZ) * (1.0f / NPART));
        }
        ws[bid] = res;
    }
}

__global__ void lj_combine(const float* __restrict__ ws,
                           float* __restrict__ out) {
    const int t = threadIdx.x;
    if (t < BATCH) out[t] = -(ws[2 * t] + ws[2 * t + 1]);
}

extern "C" void kernel_launch(void* const* d_in, const int* in_sizes, int n_in,
                              void* d_out, int out_size, void* d_ws, size_t ws_size,
                              hipStream_t stream) {
    const float* x = (const float*)d_in[0];
    float* out = (float*)d_out;
    float* pw = (float*)d_ws;   // 256 partials

    lj_main<<<BATCH * 2, 1024, 0, stream>>>(x, pw);
    lj_combine<<<1, 128, 0, stream>>>(pw, out);
}